// Round 9
// baseline (192.135 us; speedup 1.0000x reference)
//
#include <hip/hip_runtime.h>
#include <hip/hip_bf16.h>
#include <cstdint>

typedef __bf16 bf16;
typedef __bf16 bf16x4 __attribute__((ext_vector_type(4)));
typedef __bf16 bf16x8 __attribute__((ext_vector_type(8)));
typedef float f32x4 __attribute__((ext_vector_type(4)));

#define B_ 16
#define N_ 1024
#define FEAT_ 768
#define H_ 8
#define NONGT_ 20
#define M_ 10
#define POS_ 64
#define DG_ 96
#define KTOT_ 30
#define KPAD_ 32
#define ROWS_ (B_*N_)
#define SCALE_M 9.797958971132712f
#define INV_SQRT_DG 0.10206207261596575f
#define NEG_ -9.0e15f

__device__ __forceinline__ bf16x8 cvt8(float4 a, float4 b) {
  bf16x8 o;
  o[0]=(bf16)a.x; o[1]=(bf16)a.y; o[2]=(bf16)a.z; o[3]=(bf16)a.w;
  o[4]=(bf16)b.x; o[5]=(bf16)b.y; o[6]=(bf16)b.z; o[7]=(bf16)b.w;
  return o;
}

// ---------------- prep: weights + V + mk-keys ----------
__global__ void prep_kernel(const float* __restrict__ Wq, const float* __restrict__ Wk,
                            const float* __restrict__ Wout, const float* __restrict__ roi,
                            const float* __restrict__ aux, const float* __restrict__ m_v,
                            const float* __restrict__ m_k,
                            bf16* __restrict__ Wq_t, bf16* __restrict__ Wk_t,
                            bf16* __restrict__ Whi, bf16* __restrict__ Wlo,
                            bf16* __restrict__ Vbf, bf16* __restrict__ kbuf)
{
  int idx = blockIdx.x * blockDim.x + threadIdx.x;
  int stride = gridDim.x * blockDim.x;
  // Wq/Wk transpose: coalesced READS, scattered writes (stores don't stall)
  for (int i = idx; i < FEAT_*FEAT_; i += stride) {
    int k = i / FEAT_, n = i % FEAT_;           // i walks Wq row-major
    bf16 q = (bf16)Wq[i], kk = (bf16)Wk[i];
    Wq_t[(size_t)n*FEAT_ + k] = q;
    Wk_t[(size_t)n*FEAT_ + k] = kk;
    float w = Wout[i];                           // Wout rows already [(h*DG+g)][f]
    bf16 hi = (bf16)w;
    Whi[i] = hi;
    Wlo[i] = (bf16)(w - (float)hi);
  }
  for (int i = idx; i < B_*KPAD_*FEAT_; i += stride) {
    int f = i % FEAT_;
    int r = (i / FEAT_) % KPAD_;
    int b = i / (FEAT_*KPAD_);
    float v;
    if (r < NONGT_)      v = roi[((size_t)b*N_ + r)*FEAT_ + f];
    else if (r < KTOT_)  v = SCALE_M * m_v[(r-NONGT_)*FEAT_ + f] * aux[b*FEAT_ + f];
    else                 v = 0.f;
    Vbf[i] = (bf16)v;
  }
  // kbuf rows 20..31 (mk keys + zero pad); rows 0..19 written by gemm_fused small role
  for (int i = idx; i < B_*12*FEAT_; i += stride) {
    int f = i % FEAT_;
    int rr = (i / FEAT_) % 12;
    int b = i / (FEAT_*12);
    float v = (rr < M_) ? SCALE_M * m_k[rr*FEAT_ + f] * aux[b*FEAT_ + f] : 0.f;
    kbuf[((size_t)b*KPAD_ + NONGT_ + rr)*FEAT_ + f] = (bf16)v;
  }
}

// ---------------- posbias v3: one thread per (row,j), f64 accumulation ----------
// posb layout [row][j][h]; g = row*20 + j; 256B contiguous pe read per thread.
__global__ __launch_bounds__(256, 8) void posbias_kernel(
    const float* __restrict__ pe, const float* __restrict__ Wpos,
    const float* __restrict__ bpos, float* __restrict__ posb)
{
  __shared__ __align__(16) float sW[POS_*H_];
  __shared__ float sbp[H_];
  const int tid = threadIdx.x;
  sW[tid] = Wpos[tid];
  sW[256 + tid] = Wpos[256 + tid];
  if (tid < H_) sbp[tid] = bpos[tid];
  __syncthreads();
  const size_t g = (size_t)blockIdx.x*256 + tid;
  const float4* per = (const float4*)(pe + g*POS_);
  double acc[8];
  #pragma unroll
  for (int h = 0; h < 8; ++h) acc[h] = (double)sbp[h];
  #pragma unroll
  for (int p4 = 0; p4 < 16; ++p4) {
    float4 a = per[p4];
    float av[4] = {a.x, a.y, a.z, a.w};
    #pragma unroll
    for (int e = 0; e < 4; ++e) {
      const double ad = (double)av[e];
      const float* wp = sW + (p4*4 + e)*8;
      #pragma unroll
      for (int h = 0; h < 8; ++h)
        acc[h] = fma(ad, (double)wp[h], acc[h]);
    }
  }
  float o[8];
  #pragma unroll
  for (int h = 0; h < 8; ++h) {
    float x = (float)acc[h];
    o[h] = __logf(fmaxf(fmaxf(x, 0.f), 1e-6f));
  }
  float4* po = (float4*)(posb + g*8);
  po[0] = (float4){o[0], o[1], o[2], o[3]};
  po[1] = (float4){o[4], o[5], o[6], o[7]};
}

// ---------------- fused GEMM phase ----------------
// bx < 768 : Q-GEMM 128x128 block tile (128 mtiles x 6 ntiles), 64x64 per wave,
//            REGISTER-streaming (no LDS, no barriers): A-frags f32 from roi +
//            in-reg cvt, B-frags bf16 from Wq_t; both L2-resident per XCD via
//            grouped mapping. Wave TLP hides L2 latency (m114).
// bx >= 768: small GEMMs, one wave per 16x16 tile (K-GEMM from roi f32 + VW-GEMM).
__global__ __launch_bounds__(256, 3) void gemm_fused_kernel(
    const float* __restrict__ roi, const bf16* __restrict__ Wq_t,
    const float* __restrict__ bq, bf16* __restrict__ qbuf,
    const bf16* __restrict__ Wk_t, const bf16* __restrict__ Vbf,
    const bf16* __restrict__ Whi, const bf16* __restrict__ Wlo,
    const float* __restrict__ bk, bf16* __restrict__ kbuf,
    bf16* __restrict__ vwT_hi, bf16* __restrict__ vwT_lo)
{
  const int tid = threadIdx.x;
  const int w = tid >> 6, l = tid & 63;
  const int bx = blockIdx.x;
  const int fr = l & 15, fq = l >> 4, fko = fq << 3;

  if (bx < 768) {
    // ---- XCD-grouped: XCD x owns mtiles {x, x+8, ...}, 6 ctiles consecutive ----
    const int x = bx & 7, j = bx >> 3;           // j in [0,96)
    const int mbase = (x + 8*(j/6)) * 128;       // 128 mtiles total
    const int nbase = (j % 6) * 128;
    const int wr = w >> 1, wc = w & 1;
    const float* Abase = roi  + (size_t)(mbase + wr*64 + fr)*FEAT_ + fko;
    const bf16*  Bbase = Wq_t + (size_t)(nbase + wc*64 + fr)*FEAT_ + fko;
    f32x4 acc[4][4] = {};
    #pragma unroll 2
    for (int kt = 0; kt < 24; ++kt) {
      bf16x8 af[4], bff[4];
      #pragma unroll
      for (int m = 0; m < 4; ++m) {
        const float* ap = Abase + (size_t)m*16*FEAT_ + kt*32;
        af[m] = cvt8(*(const float4*)ap, *(const float4*)(ap + 4));
      }
      #pragma unroll
      for (int n = 0; n < 4; ++n)
        bff[n] = *(const bf16x8*)(Bbase + (size_t)n*16*FEAT_ + kt*32);
      #pragma unroll
      for (int m = 0; m < 4; ++m) {
        #pragma unroll
        for (int n = 0; n < 4; ++n)
          acc[m][n] = __builtin_amdgcn_mfma_f32_16x16x32_bf16(af[m], bff[n], acc[m][n], 0, 0, 0);
      }
    }
    #pragma unroll
    for (int n = 0; n < 4; ++n) {
      const int col = nbase + wc*64 + n*16 + fr;
      const float bv = bq[col];
      #pragma unroll
      for (int m = 0; m < 4; ++m) {
        const int row = mbase + wr*64 + m*16 + fq*4;
        #pragma unroll
        for (int r = 0; r < 4; ++r)
          qbuf[(size_t)(row + r)*FEAT_ + col] = (bf16)(acc[m][n][r] + bv);
      }
    }
  } else {
    // ---- small GEMMs: wave-task widx in [0, 3072) ----
    const int widx = (bx - 768)*4 + w;
    const int cbase = (widx % 48) * 16;
    const int by = widx / 48;                 // [0,64)
    f32x4 acc = {};
    if (by < 32) {
      const float* Ap = roi + ((size_t)(by >> 1)*N_ + (by & 1)*16 + fr)*FEAT_ + fko;
      const bf16* Bp = Wk_t + (size_t)(cbase + fr)*FEAT_ + fko;
      #pragma unroll
      for (int kt = 0; kt < FEAT_/32; ++kt) {
        float4 a0 = *(const float4*)(Ap + kt*32);
        float4 a1 = *(const float4*)(Ap + kt*32 + 4);
        bf16x8 b = *(const bf16x8*)(Bp + kt*32);
        acc = __builtin_amdgcn_mfma_f32_16x16x32_bf16(cvt8(a0, a1), b, acc, 0, 0, 0);
      }
      const float bv = bk[cbase + fr];
      #pragma unroll
      for (int r = 0; r < 4; ++r) {
        const int rl = (by & 1)*16 + fq*4 + r;       // local key row 0..31
        if (rl < NONGT_)
          kbuf[((size_t)(by >> 1)*KPAD_ + rl)*FEAT_ + cbase + fr] = (bf16)(acc[r] + bv);
      }
    } else {
      const int rt = by - 32;
      const bf16* Ap = Vbf + ((size_t)rt*16 + fr)*FEAT_ + fko;
      const bf16* B1 = Whi + (size_t)(cbase + fr)*FEAT_ + fko;
      const bf16* B2 = Wlo + (size_t)(cbase + fr)*FEAT_ + fko;
      f32x4 acc2 = {};
      #pragma unroll
      for (int kt = 0; kt < FEAT_/32; ++kt) {
        bf16x8 a = *(const bf16x8*)(Ap + kt*32);
        acc  = __builtin_amdgcn_mfma_f32_16x16x32_bf16(a, *(const bf16x8*)(B1 + kt*32), acc,  0, 0, 0);
        acc2 = __builtin_amdgcn_mfma_f32_16x16x32_bf16(a, *(const bf16x8*)(B2 + kt*32), acc2, 0, 0, 0);
      }
      #pragma unroll
      for (int r = 0; r < 4; ++r) {
        const int grow = rt*16 + fq*4 + r;           // 0..511
        const int b = grow >> 5, key = grow & 31;
        float vv = acc[r] + acc2[r];
        bf16 vh = (bf16)vv;
        size_t addr = ((size_t)b*FEAT_ + cbase + fr)*KPAD_ + key;
        vwT_hi[addr] = vh;
        vwT_lo[addr] = (bf16)(vv - (float)vh);
      }
    }
  }
}

// ---------------- fused attention: QK^T (MFMA) + softmax + PV (MFMA) ----------------
// grid (ntile=64, b=16), 256 threads = 4 waves; wave w owns heads 2w, 2w+1.
__global__ __launch_bounds__(256, 4) void attn_kernel(
    const bf16* __restrict__ qbuf, const bf16* __restrict__ kbuf,
    const bf16* __restrict__ vwT_hi, const bf16* __restrict__ vwT_lo,
    const float* __restrict__ posb, const int* __restrict__ adj,
    const float* __restrict__ lb, const float* __restrict__ bout,
    float* __restrict__ out)
{
  __shared__ __align__(16) bf16 sph[H_*16*40];   // p hi, padded key stride 40
  __shared__ __align__(16) bf16 spl[H_*16*40];   // p lo
  const int tid = threadIdx.x;
  const int w = tid >> 6, l = tid & 63;
  const int fr = l & 15, fq = l >> 4, fko = fq << 3;
  const int row0 = blockIdx.x * 16;
  const int b = blockIdx.y;
  const size_t rabs = (size_t)b*N_ + row0 + fr;   // this lane's q-row (for q/posb/adj/lb)

  #pragma unroll
  for (int hi2 = 0; hi2 < 2; ++hi2) {
    const int h = w*2 + hi2;
    // ---- QK^T: C[key][qrow], 2 key-tiles, K=96 ----
    const bf16* kp = kbuf + (size_t)b*KPAD_*FEAT_ + h*DG_ + fko;
    const bf16* qp = qbuf + rabs*FEAT_ + h*DG_ + fko;
    f32x4 acc0 = {}, acc1 = {};
    #pragma unroll
    for (int kt = 0; kt < 3; ++kt) {
      bf16x8 qa = *(const bf16x8*)(qp + kt*32);
      bf16x8 k0 = *(const bf16x8*)(kp + (size_t)fr*FEAT_ + kt*32);
      bf16x8 k1 = *(const bf16x8*)(kp + (size_t)(16 + fr)*FEAT_ + kt*32);
      acc0 = __builtin_amdgcn_mfma_f32_16x16x32_bf16(k0, qa, acc0, 0, 0, 0);
      acc1 = __builtin_amdgcn_mfma_f32_16x16x32_bf16(k1, qa, acc1, 0, 0, 0);
    }
    // ---- bias + mask; lane holds keys {fq*4+r, 16+fq*4+r} of q-row (row0+fr) ----
    const float* pbr = posb + rabs*160;            // layout [j][h]
    const int*   adjr = adj + rabs*20;
    const float* lbr  = lb  + rabs*20;
    float lg[2][4];
    #pragma unroll
    for (int r = 0; r < 4; ++r) {
      int j0 = fq*4 + r;
      float v0 = acc0[r] * INV_SQRT_DG;
      v0 = (adjr[j0] > 0 ? v0 + pbr[j0*8 + h] : NEG_) + lbr[j0];
      lg[0][r] = v0;
      int j1 = 16 + fq*4 + r;
      float v1 = acc1[r] * INV_SQRT_DG;
      if (j1 < NONGT_)      v1 = (adjr[j1] > 0 ? v1 + pbr[j1*8 + h] : NEG_) + lbr[j1];
      else if (j1 >= KTOT_) v1 = -3.0e38f;
      lg[1][r] = v1;
    }
    // ---- softmax over 32 keys: 8 regs x 4 lanes (fq) ----
    float m = lg[0][0];
    #pragma unroll
    for (int jt = 0; jt < 2; ++jt)
      #pragma unroll
      for (int r = 0; r < 4; ++r) m = fmaxf(m, lg[jt][r]);
    m = fmaxf(m, __shfl_xor(m, 16));
    m = fmaxf(m, __shfl_xor(m, 32));
    float s = 0.f;
    float e[2][4];
    #pragma unroll
    for (int jt = 0; jt < 2; ++jt)
      #pragma unroll
      for (int r = 0; r < 4; ++r) { e[jt][r] = __expf(lg[jt][r] - m); s += e[jt][r]; }
    s += __shfl_xor(s, 16);
    s += __shfl_xor(s, 32);
    const float inv = 1.f / s;
    // ---- p -> hi/lo bf16 -> LDS (wave-private region, no barrier) ----
    #pragma unroll
    for (int jt = 0; jt < 2; ++jt) {
      bf16x4 ph, pl;
      #pragma unroll
      for (int r = 0; r < 4; ++r) {
        float p = e[jt][r] * inv;
        ph[r] = (bf16)p;
        pl[r] = (bf16)(p - (float)ph[r]);
      }
      const int off = (h*16 + fr)*40 + jt*16 + fq*4;
      *(bf16x4*)(sph + off) = ph;
      *(bf16x4*)(spl + off) = pl;
    }
    // ---- PV: out[16 rows x 96 cols] via 6 col-tiles, K=32 (1 k-step), 3 passes ----
    bf16x8 pa_h = *(const bf16x8*)(sph + (h*16 + fr)*40 + fko);
    bf16x8 pa_l = *(const bf16x8*)(spl + (h*16 + fr)*40 + fko);
    #pragma unroll
    for (int ct = 0; ct < 6; ++ct) {
      const int col = h*DG_ + ct*16 + fr;
      const size_t vaddr = ((size_t)b*FEAT_ + col)*KPAD_ + fko;
      bf16x8 vh = *(const bf16x8*)(vwT_hi + vaddr);
      bf16x8 vl = *(const bf16x8*)(vwT_lo + vaddr);
      f32x4 o = {};
      o = __builtin_amdgcn_mfma_f32_16x16x32_bf16(pa_h, vh, o, 0, 0, 0);
      o = __builtin_amdgcn_mfma_f32_16x16x32_bf16(pa_h, vl, o, 0, 0, 0);
      o = __builtin_amdgcn_mfma_f32_16x16x32_bf16(pa_l, vh, o, 0, 0, 0);
      const float bv = bout[col];
      #pragma unroll
      for (int r = 0; r < 4; ++r)
        out[((size_t)b*N_ + row0 + fq*4 + r)*FEAT_ + col] = o[r] + bv;
    }
  }
}

extern "C" void kernel_launch(void* const* d_in, const int* in_sizes, int n_in,
                              void* d_out, int out_size, void* d_ws, size_t ws_size,
                              hipStream_t stream) {
  const float* roi  = (const float*)d_in[0];
  const int*   adj  = (const int*)  d_in[1];
  const float* pe   = (const float*)d_in[2];
  const float* lb   = (const float*)d_in[3];
  const float* aux  = (const float*)d_in[4];
  const float* Wq   = (const float*)d_in[5];
  const float* bq   = (const float*)d_in[6];
  const float* Wk   = (const float*)d_in[7];
  const float* bk   = (const float*)d_in[8];
  const float* Wpos = (const float*)d_in[9];
  const float* bpos = (const float*)d_in[10];
  const float* m_k  = (const float*)d_in[11];
  const float* m_v  = (const float*)d_in[12];
  const float* Wout = (const float*)d_in[13];
  const float* bout = (const float*)d_in[14];
  float* out = (float*)d_out;

  char* pw = (char*)d_ws;
  auto carve = [&](size_t bytes) -> void* {
    void* r = pw; pw += (bytes + 255) & ~(size_t)255; return r;
  };
  bf16*  qbuf   = (bf16*) carve((size_t)ROWS_*FEAT_*2);
  bf16*  Wq_t   = (bf16*) carve((size_t)FEAT_*FEAT_*2);
  bf16*  Wk_t   = (bf16*) carve((size_t)FEAT_*FEAT_*2);
  bf16*  Whi    = (bf16*) carve((size_t)FEAT_*FEAT_*2);
  bf16*  Wlo    = (bf16*) carve((size_t)FEAT_*FEAT_*2);
  bf16*  Vbf    = (bf16*) carve((size_t)B_*KPAD_*FEAT_*2);
  bf16*  kbuf   = (bf16*) carve((size_t)B_*KPAD_*FEAT_*2);
  bf16*  vwT_hi = (bf16*) carve((size_t)B_*FEAT_*KPAD_*2);
  bf16*  vwT_lo = (bf16*) carve((size_t)B_*FEAT_*KPAD_*2);
  float* posb   = (float*)carve((size_t)ROWS_*160*4);

  posbias_kernel<<<dim3(ROWS_*NONGT_/256), dim3(256), 0, stream>>>(pe, Wpos, bpos, posb);
  prep_kernel<<<dim3(1024), dim3(256), 0, stream>>>(Wq, Wk, Wout, roi, aux, m_v, m_k,
                                                    Wq_t, Wk_t, Whi, Wlo, Vbf, kbuf);
  gemm_fused_kernel<<<dim3(1536), dim3(256), 0, stream>>>(roi, Wq_t, bq, qbuf,
                                                          Wk_t, Vbf, Whi, Wlo, bk, kbuf,
                                                          vwT_hi, vwT_lo);
  attn_kernel<<<dim3(64, 16), dim3(256), 0, stream>>>(qbuf, kbuf, vwT_hi, vwT_lo,
                                                      posb, adj, lb, bout, out);
}

// Round 10
// 134.005 us; speedup vs baseline: 1.4338x; 1.4338x over previous
//
#include <hip/hip_runtime.h>
#include <hip/hip_bf16.h>
#include <cstdint>

typedef __bf16 bf16;
typedef __bf16 bf16x4 __attribute__((ext_vector_type(4)));
typedef __bf16 bf16x8 __attribute__((ext_vector_type(8)));
typedef float f32x4 __attribute__((ext_vector_type(4)));

#define B_ 16
#define N_ 1024
#define FEAT_ 768
#define H_ 8
#define NONGT_ 20
#define M_ 10
#define POS_ 64
#define DG_ 96
#define KTOT_ 30
#define KPAD_ 32
#define ROWS_ (B_*N_)
#define SCALE_M 9.797958971132712f
#define INV_SQRT_DG 0.10206207261596575f
#define NEG_ -9.0e15f

__device__ __forceinline__ void gload16(const void* g, void* lds) {
  __builtin_amdgcn_global_load_lds(
      (const __attribute__((address_space(1))) unsigned int*)g,
      (__attribute__((address_space(3))) unsigned int*)lds, 16, 0, 0);
}

__device__ __forceinline__ bf16x8 cvt8(float4 a, float4 b) {
  bf16x8 o;
  o[0]=(bf16)a.x; o[1]=(bf16)a.y; o[2]=(bf16)a.z; o[3]=(bf16)a.w;
  o[4]=(bf16)b.x; o[5]=(bf16)b.y; o[6]=(bf16)b.z; o[7]=(bf16)b.w;
  return o;
}

// ---------------- prep: weights + V + mk-keys + roi->Abf (pre-swizzled) ----------
// Abf and Wq_t carry an LDS-bank swizzle: within each 32-elem k-block, 8-elem slot
// s -> s ^ ((row>>1)&3). gload_lds stages them linearly; gemm reads with the same
// XOR => ds_read_b128 bank conflicts drop 8-way -> <=2-way (free). (rule #21)
__global__ void prep_kernel(const float* __restrict__ Wq, const float* __restrict__ Wk,
                            const float* __restrict__ Wout, const float* __restrict__ roi,
                            const float* __restrict__ aux, const float* __restrict__ m_v,
                            const float* __restrict__ m_k,
                            bf16* __restrict__ Wq_t, bf16* __restrict__ Wk_t,
                            bf16* __restrict__ Whi, bf16* __restrict__ Wlo,
                            bf16* __restrict__ Vbf, bf16* __restrict__ kbuf,
                            bf16* __restrict__ Abf)
{
  int idx = blockIdx.x * blockDim.x + threadIdx.x;
  int stride = gridDim.x * blockDim.x;
  for (int i = idx; i < FEAT_*FEAT_; i += stride) {
    int k = i / FEAT_, n = i % FEAT_;            // i walks Wq row-major: Wq[k][n]
    // Wq_t[n][k] with slot swizzle on k (read by gemm role A via LDS tiles)
    int ksw = (k & ~31) | (((((k >> 3) & 3) ^ ((n >> 1) & 3))) << 3) | (k & 7);
    Wq_t[(size_t)n*FEAT_ + ksw] = (bf16)Wq[i];
    Wk_t[(size_t)n*FEAT_ + k]   = (bf16)Wk[i];   // normal layout (read per-lane direct)
    float w = Wout[i];
    bf16 hi = (bf16)w;
    Whi[i] = hi;
    Wlo[i] = (bf16)(w - (float)hi);
  }
  for (int i = idx; i < B_*KPAD_*FEAT_; i += stride) {
    int f = i % FEAT_;
    int r = (i / FEAT_) % KPAD_;
    int b = i / (FEAT_*KPAD_);
    float v;
    if (r < NONGT_)      v = roi[((size_t)b*N_ + r)*FEAT_ + f];
    else if (r < KTOT_)  v = SCALE_M * m_v[(r-NONGT_)*FEAT_ + f] * aux[b*FEAT_ + f];
    else                 v = 0.f;
    Vbf[i] = (bf16)v;
  }
  for (int i = idx; i < B_*12*FEAT_; i += stride) {
    int f = i % FEAT_;
    int rr = (i / FEAT_) % 12;
    int b = i / (FEAT_*12);
    float v = (rr < M_) ? SCALE_M * m_k[rr*FEAT_ + f] * aux[b*FEAT_ + f] : 0.f;
    kbuf[((size_t)b*KPAD_ + NONGT_ + rr)*FEAT_ + f] = (bf16)v;
  }
  // roi -> Abf bf16, pre-swizzled (coalesced read, 32B-local scattered write)
  const int total8 = ROWS_*FEAT_/8;
  for (int i = idx; i < total8; i += stride) {
    int row = i / (FEAT_/8);
    int col = (i % (FEAT_/8)) * 8;
    int slot_sw = ((col >> 3) & 3) ^ ((row >> 1) & 3);
    const float4* p = (const float4*)(roi + (size_t)i*8);
    *(bf16x8*)(Abf + (size_t)row*FEAT_ + (col & ~31) + slot_sw*8) = cvt8(p[0], p[1]);
  }
}

// ---------------- posbias v3: one thread per (row,j), f64 accumulation ----------
__global__ __launch_bounds__(256, 8) void posbias_kernel(
    const float* __restrict__ pe, const float* __restrict__ Wpos,
    const float* __restrict__ bpos, float* __restrict__ posb)
{
  __shared__ __align__(16) float sW[POS_*H_];
  __shared__ float sbp[H_];
  const int tid = threadIdx.x;
  sW[tid] = Wpos[tid];
  sW[256 + tid] = Wpos[256 + tid];
  if (tid < H_) sbp[tid] = bpos[tid];
  __syncthreads();
  const size_t g = (size_t)blockIdx.x*256 + tid;
  const float4* per = (const float4*)(pe + g*POS_);
  double acc[8];
  #pragma unroll
  for (int h = 0; h < 8; ++h) acc[h] = (double)sbp[h];
  #pragma unroll
  for (int p4 = 0; p4 < 16; ++p4) {
    float4 a = per[p4];
    float av[4] = {a.x, a.y, a.z, a.w};
    #pragma unroll
    for (int e = 0; e < 4; ++e) {
      const double ad = (double)av[e];
      const float* wp = sW + (p4*4 + e)*8;
      #pragma unroll
      for (int h = 0; h < 8; ++h)
        acc[h] = fma(ad, (double)wp[h], acc[h]);
    }
  }
  float o[8];
  #pragma unroll
  for (int h = 0; h < 8; ++h) {
    float x = (float)acc[h];
    o[h] = __logf(fmaxf(fmaxf(x, 0.f), 1e-6f));
  }
  float4* po = (float4*)(posb + g*8);
  po[0] = (float4){o[0], o[1], o[2], o[3]};
  po[1] = (float4){o[4], o[5], o[6], o[7]};
}

// ---------------- fused GEMM phase (R4 structure + swizzled LDS reads) ----------
// bx < 768 : Q-GEMM 128x128 tile, XCD-grouped; A/B staged via gload_lds from
//            pre-swizzled Abf/Wq_t; fragment ds_reads use the XOR'd slot.
// bx >= 768: small GEMMs, one wave per 16x16 tile.
__global__ __launch_bounds__(256, 2) void gemm_fused_kernel(
    const bf16* __restrict__ Abf, const float* __restrict__ roi,
    const bf16* __restrict__ Wq_t,
    const float* __restrict__ bq, bf16* __restrict__ qbuf,
    const bf16* __restrict__ Wk_t, const bf16* __restrict__ Vbf,
    const bf16* __restrict__ Whi, const bf16* __restrict__ Wlo,
    const float* __restrict__ bk, bf16* __restrict__ kbuf,
    bf16* __restrict__ vwT_hi, bf16* __restrict__ vwT_lo)
{
  __shared__ __align__(16) bf16 sA[128*32];
  __shared__ __align__(16) bf16 sB[128*32];
  const int tid = threadIdx.x;
  const int w = tid >> 6, l = tid & 63;
  const int bx = blockIdx.x;
  const int fr = l & 15, fq = l >> 4, fko = fq << 3;

  if (bx < 768) {
    const int x = bx & 7, j = bx >> 3;           // j in [0,96)
    const int mbase = (x + 8*(j/6)) * 128;       // 128 mtiles
    const int nbase = (j % 6) * 128;
    const int wr = w >> 1, wc = w & 1;
    const int srow = tid >> 2;
    const int scol = (tid & 3) << 3;
    const bf16* Ag0 = Abf + (size_t)(mbase + srow)*FEAT_ + scol;
    const bf16* Ag1 = Ag0 + (size_t)64*FEAT_;
    const bf16* Bg0 = Wq_t + (size_t)(nbase + srow)*FEAT_ + scol;
    const bf16* Bg1 = Bg0 + (size_t)64*FEAT_;
    bf16* ldsA0 = sA + w*512;
    bf16* ldsA1 = sA + 2048 + w*512;
    bf16* ldsB0 = sB + w*512;
    bf16* ldsB1 = sB + 2048 + w*512;
    // swizzled fragment slot: logical fq -> physical fq ^ ((row>>1)&3); row&3 dep = fr only
    const int fko_sw = ((fq ^ ((fr >> 1) & 3)) << 3);
    f32x4 acc[4][4] = {};
    for (int kt = 0; kt < FEAT_/32; ++kt) {
      __syncthreads();
      gload16(Ag0 + kt*32, ldsA0);
      gload16(Ag1 + kt*32, ldsA1);
      gload16(Bg0 + kt*32, ldsB0);
      gload16(Bg1 + kt*32, ldsB1);
      __syncthreads();
      bf16x8 af[4], bff[4];
      #pragma unroll
      for (int m = 0; m < 4; ++m)
        af[m] = *(const bf16x8*)(sA + (wr*64 + m*16 + fr)*32 + fko_sw);
      #pragma unroll
      for (int n = 0; n < 4; ++n)
        bff[n] = *(const bf16x8*)(sB + (wc*64 + n*16 + fr)*32 + fko_sw);
      #pragma unroll
      for (int m = 0; m < 4; ++m) {
        #pragma unroll
        for (int n = 0; n < 4; ++n)
          acc[m][n] = __builtin_amdgcn_mfma_f32_16x16x32_bf16(af[m], bff[n], acc[m][n], 0, 0, 0);
      }
    }
    #pragma unroll
    for (int n = 0; n < 4; ++n) {
      const int col = nbase + wc*64 + n*16 + fr;
      const float bv = bq[col];
      #pragma unroll
      for (int m = 0; m < 4; ++m) {
        const int row = mbase + wr*64 + m*16 + fq*4;
        #pragma unroll
        for (int r = 0; r < 4; ++r)
          qbuf[(size_t)(row + r)*FEAT_ + col] = (bf16)(acc[m][n][r] + bv);
      }
    }
  } else {
    // ---- small GEMMs: wave-task widx in [0, 3072) ----
    const int widx = (bx - 768)*4 + w;
    const int cbase = (widx % 48) * 16;
    const int by = widx / 48;                 // [0,64)
    f32x4 acc = {};
    if (by < 32) {
      const float* Ap = roi + ((size_t)(by >> 1)*N_ + (by & 1)*16 + fr)*FEAT_ + fko;
      const bf16* Bp = Wk_t + (size_t)(cbase + fr)*FEAT_ + fko;
      #pragma unroll
      for (int kt = 0; kt < FEAT_/32; ++kt) {
        float4 a0 = *(const float4*)(Ap + kt*32);
        float4 a1 = *(const float4*)(Ap + kt*32 + 4);
        bf16x8 b = *(const bf16x8*)(Bp + kt*32);
        acc = __builtin_amdgcn_mfma_f32_16x16x32_bf16(cvt8(a0, a1), b, acc, 0, 0, 0);
      }
      const float bv = bk[cbase + fr];
      #pragma unroll
      for (int r = 0; r < 4; ++r) {
        const int rl = (by & 1)*16 + fq*4 + r;
        if (rl < NONGT_)
          kbuf[((size_t)(by >> 1)*KPAD_ + rl)*FEAT_ + cbase + fr] = (bf16)(acc[r] + bv);
      }
    } else {
      const int rt = by - 32;
      const bf16* Ap = Vbf + ((size_t)rt*16 + fr)*FEAT_ + fko;
      const bf16* B1 = Whi + (size_t)(cbase + fr)*FEAT_ + fko;
      const bf16* B2 = Wlo + (size_t)(cbase + fr)*FEAT_ + fko;
      f32x4 acc2 = {};
      #pragma unroll
      for (int kt = 0; kt < FEAT_/32; ++kt) {
        bf16x8 a = *(const bf16x8*)(Ap + kt*32);
        acc  = __builtin_amdgcn_mfma_f32_16x16x32_bf16(a, *(const bf16x8*)(B1 + kt*32), acc,  0, 0, 0);
        acc2 = __builtin_amdgcn_mfma_f32_16x16x32_bf16(a, *(const bf16x8*)(B2 + kt*32), acc2, 0, 0, 0);
      }
      #pragma unroll
      for (int r = 0; r < 4; ++r) {
        const int grow = rt*16 + fq*4 + r;
        const int b = grow >> 5, key = grow & 31;
        float vv = acc[r] + acc2[r];
        bf16 vh = (bf16)vv;
        size_t addr = ((size_t)b*FEAT_ + cbase + fr)*KPAD_ + key;
        vwT_hi[addr] = vh;
        vwT_lo[addr] = (bf16)(vv - (float)vh);
      }
    }
  }
}

// ---------------- fused attention: QK^T (MFMA) + softmax + PV (MFMA) ----------------
__global__ __launch_bounds__(256, 4) void attn_kernel(
    const bf16* __restrict__ qbuf, const bf16* __restrict__ kbuf,
    const bf16* __restrict__ vwT_hi, const bf16* __restrict__ vwT_lo,
    const float* __restrict__ posb, const int* __restrict__ adj,
    const float* __restrict__ lb, const float* __restrict__ bout,
    float* __restrict__ out)
{
  __shared__ __align__(16) bf16 sph[H_*16*40];
  __shared__ __align__(16) bf16 spl[H_*16*40];
  const int tid = threadIdx.x;
  const int w = tid >> 6, l = tid & 63;
  const int fr = l & 15, fq = l >> 4, fko = fq << 3;
  const int row0 = blockIdx.x * 16;
  const int b = blockIdx.y;
  const size_t rabs = (size_t)b*N_ + row0 + fr;

  #pragma unroll
  for (int hi2 = 0; hi2 < 2; ++hi2) {
    const int h = w*2 + hi2;
    const bf16* kp = kbuf + (size_t)b*KPAD_*FEAT_ + h*DG_ + fko;
    const bf16* qp = qbuf + rabs*FEAT_ + h*DG_ + fko;
    f32x4 acc0 = {}, acc1 = {};
    #pragma unroll
    for (int kt = 0; kt < 3; ++kt) {
      bf16x8 qa = *(const bf16x8*)(qp + kt*32);
      bf16x8 k0 = *(const bf16x8*)(kp + (size_t)fr*FEAT_ + kt*32);
      bf16x8 k1 = *(const bf16x8*)(kp + (size_t)(16 + fr)*FEAT_ + kt*32);
      acc0 = __builtin_amdgcn_mfma_f32_16x16x32_bf16(k0, qa, acc0, 0, 0, 0);
      acc1 = __builtin_amdgcn_mfma_f32_16x16x32_bf16(k1, qa, acc1, 0, 0, 0);
    }
    const float* pbr = posb + rabs*160;            // layout [j][h]
    const int*   adjr = adj + rabs*20;
    const float* lbr  = lb  + rabs*20;
    float lg[2][4];
    #pragma unroll
    for (int r = 0; r < 4; ++r) {
      int j0 = fq*4 + r;
      float v0 = acc0[r] * INV_SQRT_DG;
      v0 = (adjr[j0] > 0 ? v0 + pbr[j0*8 + h] : NEG_) + lbr[j0];
      lg[0][r] = v0;
      int j1 = 16 + fq*4 + r;
      float v1 = acc1[r] * INV_SQRT_DG;
      if (j1 < NONGT_)      v1 = (adjr[j1] > 0 ? v1 + pbr[j1*8 + h] : NEG_) + lbr[j1];
      else if (j1 >= KTOT_) v1 = -3.0e38f;
      lg[1][r] = v1;
    }
    float m = lg[0][0];
    #pragma unroll
    for (int jt = 0; jt < 2; ++jt)
      #pragma unroll
      for (int r = 0; r < 4; ++r) m = fmaxf(m, lg[jt][r]);
    m = fmaxf(m, __shfl_xor(m, 16));
    m = fmaxf(m, __shfl_xor(m, 32));
    float s = 0.f;
    float e[2][4];
    #pragma unroll
    for (int jt = 0; jt < 2; ++jt)
      #pragma unroll
      for (int r = 0; r < 4; ++r) { e[jt][r] = __expf(lg[jt][r] - m); s += e[jt][r]; }
    s += __shfl_xor(s, 16);
    s += __shfl_xor(s, 32);
    const float inv = 1.f / s;
    #pragma unroll
    for (int jt = 0; jt < 2; ++jt) {
      bf16x4 ph, pl;
      #pragma unroll
      for (int r = 0; r < 4; ++r) {
        float p = e[jt][r] * inv;
        ph[r] = (bf16)p;
        pl[r] = (bf16)(p - (float)ph[r]);
      }
      const int off = (h*16 + fr)*40 + jt*16 + fq*4;
      *(bf16x4*)(sph + off) = ph;
      *(bf16x4*)(spl + off) = pl;
    }
    bf16x8 pa_h = *(const bf16x8*)(sph + (h*16 + fr)*40 + fko);
    bf16x8 pa_l = *(const bf16x8*)(spl + (h*16 + fr)*40 + fko);
    #pragma unroll
    for (int ct = 0; ct < 6; ++ct) {
      const int col = h*DG_ + ct*16 + fr;
      const size_t vaddr = ((size_t)b*FEAT_ + col)*KPAD_ + fko;
      bf16x8 vh = *(const bf16x8*)(vwT_hi + vaddr);
      bf16x8 vl = *(const bf16x8*)(vwT_lo + vaddr);
      f32x4 o = {};
      o = __builtin_amdgcn_mfma_f32_16x16x32_bf16(pa_h, vh, o, 0, 0, 0);
      o = __builtin_amdgcn_mfma_f32_16x16x32_bf16(pa_h, vl, o, 0, 0, 0);
      o = __builtin_amdgcn_mfma_f32_16x16x32_bf16(pa_l, vh, o, 0, 0, 0);
      const float bv = bout[col];
      #pragma unroll
      for (int r = 0; r < 4; ++r)
        out[((size_t)b*N_ + row0 + fq*4 + r)*FEAT_ + col] = o[r] + bv;
    }
  }
}

extern "C" void kernel_launch(void* const* d_in, const int* in_sizes, int n_in,
                              void* d_out, int out_size, void* d_ws, size_t ws_size,
                              hipStream_t stream) {
  const float* roi  = (const float*)d_in[0];
  const int*   adj  = (const int*)  d_in[1];
  const float* pe   = (const float*)d_in[2];
  const float* lb   = (const float*)d_in[3];
  const float* aux  = (const float*)d_in[4];
  const float* Wq   = (const float*)d_in[5];
  const float* bq   = (const float*)d_in[6];
  const float* Wk   = (const float*)d_in[7];
  const float* bk   = (const float*)d_in[8];
  const float* Wpos = (const float*)d_in[9];
  const float* bpos = (const float*)d_in[10];
  const float* m_k  = (const float*)d_in[11];
  const float* m_v  = (const float*)d_in[12];
  const float* Wout = (const float*)d_in[13];
  const float* bout = (const float*)d_in[14];
  float* out = (float*)d_out;

  char* pw = (char*)d_ws;
  auto carve = [&](size_t bytes) -> void* {
    void* r = pw; pw += (bytes + 255) & ~(size_t)255; return r;
  };
  bf16*  Abf    = (bf16*) carve((size_t)ROWS_*FEAT_*2);
  bf16*  qbuf   = (bf16*) carve((size_t)ROWS_*FEAT_*2);
  bf16*  Wq_t   = (bf16*) carve((size_t)FEAT_*FEAT_*2);
  bf16*  Wk_t   = (bf16*) carve((size_t)FEAT_*FEAT_*2);
  bf16*  Whi    = (bf16*) carve((size_t)FEAT_*FEAT_*2);
  bf16*  Wlo    = (bf16*) carve((size_t)FEAT_*FEAT_*2);
  bf16*  Vbf    = (bf16*) carve((size_t)B_*KPAD_*FEAT_*2);
  bf16*  kbuf   = (bf16*) carve((size_t)B_*KPAD_*FEAT_*2);
  bf16*  vwT_hi = (bf16*) carve((size_t)B_*FEAT_*KPAD_*2);
  bf16*  vwT_lo = (bf16*) carve((size_t)B_*FEAT_*KPAD_*2);
  float* posb   = (float*)carve((size_t)ROWS_*160*4);

  posbias_kernel<<<dim3(ROWS_*NONGT_/256), dim3(256), 0, stream>>>(pe, Wpos, bpos, posb);
  prep_kernel<<<dim3(2048), dim3(256), 0, stream>>>(Wq, Wk, Wout, roi, aux, m_v, m_k,
                                                    Wq_t, Wk_t, Whi, Wlo, Vbf, kbuf, Abf);
  gemm_fused_kernel<<<dim3(1536), dim3(256), 0, stream>>>(Abf, roi, Wq_t, bq, qbuf,
                                                          Wk_t, Vbf, Whi, Wlo, bk, kbuf,
                                                          vwT_hi, vwT_lo);
  attn_kernel<<<dim3(64, 16), dim3(256), 0, stream>>>(qbuf, kbuf, vwT_hi, vwT_lo,
                                                      posb, adj, lb, bout, out);
}

// Round 11
// 128.190 us; speedup vs baseline: 1.4988x; 1.0454x over previous
//
#include <hip/hip_runtime.h>
#include <hip/hip_bf16.h>
#include <cstdint>

typedef __bf16 bf16;
typedef __bf16 bf16x4 __attribute__((ext_vector_type(4)));
typedef __bf16 bf16x8 __attribute__((ext_vector_type(8)));
typedef float f32x4 __attribute__((ext_vector_type(4)));

#define B_ 16
#define N_ 1024
#define FEAT_ 768
#define H_ 8
#define NONGT_ 20
#define M_ 10
#define POS_ 64
#define DG_ 96
#define KTOT_ 30
#define KPAD_ 32
#define ROWS_ (B_*N_)
#define SCALE_M 9.797958971132712f
#define INV_SQRT_DG 0.10206207261596575f
#define NEG_ -9.0e15f

__device__ __forceinline__ void gload16(const void* g, void* lds) {
  __builtin_amdgcn_global_load_lds(
      (const __attribute__((address_space(1))) unsigned int*)g,
      (__attribute__((address_space(3))) unsigned int*)lds, 16, 0, 0);
}

__device__ __forceinline__ bf16x8 cvt8(float4 a, float4 b) {
  bf16x8 o;
  o[0]=(bf16)a.x; o[1]=(bf16)a.y; o[2]=(bf16)a.z; o[3]=(bf16)a.w;
  o[4]=(bf16)b.x; o[5]=(bf16)b.y; o[6]=(bf16)b.z; o[7]=(bf16)b.w;
  return o;
}

// ---------------- prep: weights + V + mk-keys + roi->Abf (pre-swizzled) ----------
__global__ void prep_kernel(const float* __restrict__ Wq, const float* __restrict__ Wk,
                            const float* __restrict__ Wout, const float* __restrict__ roi,
                            const float* __restrict__ aux, const float* __restrict__ m_v,
                            const float* __restrict__ m_k,
                            bf16* __restrict__ Wq_t, bf16* __restrict__ Wk_t,
                            bf16* __restrict__ Whi, bf16* __restrict__ Wlo,
                            bf16* __restrict__ Vbf, bf16* __restrict__ kbuf,
                            bf16* __restrict__ Abf)
{
  int idx = blockIdx.x * blockDim.x + threadIdx.x;
  int stride = gridDim.x * blockDim.x;
  for (int i = idx; i < FEAT_*FEAT_; i += stride) {
    int k = i / FEAT_, n = i % FEAT_;            // i walks Wq row-major: Wq[k][n]
    int ksw = (k & ~31) | (((((k >> 3) & 3) ^ ((n >> 1) & 3))) << 3) | (k & 7);
    Wq_t[(size_t)n*FEAT_ + ksw] = (bf16)Wq[i];
    Wk_t[(size_t)n*FEAT_ + k]   = (bf16)Wk[i];
    float w = Wout[i];
    bf16 hi = (bf16)w;
    Whi[i] = hi;
    Wlo[i] = (bf16)(w - (float)hi);
  }
  for (int i = idx; i < B_*KPAD_*FEAT_; i += stride) {
    int f = i % FEAT_;
    int r = (i / FEAT_) % KPAD_;
    int b = i / (FEAT_*KPAD_);
    float v;
    if (r < NONGT_)      v = roi[((size_t)b*N_ + r)*FEAT_ + f];
    else if (r < KTOT_)  v = SCALE_M * m_v[(r-NONGT_)*FEAT_ + f] * aux[b*FEAT_ + f];
    else                 v = 0.f;
    Vbf[i] = (bf16)v;
  }
  for (int i = idx; i < B_*12*FEAT_; i += stride) {
    int f = i % FEAT_;
    int rr = (i / FEAT_) % 12;
    int b = i / (FEAT_*12);
    float v = (rr < M_) ? SCALE_M * m_k[rr*FEAT_ + f] * aux[b*FEAT_ + f] : 0.f;
    kbuf[((size_t)b*KPAD_ + NONGT_ + rr)*FEAT_ + f] = (bf16)v;
  }
  const int total8 = ROWS_*FEAT_/8;
  for (int i = idx; i < total8; i += stride) {
    int row = i / (FEAT_/8);
    int col = (i % (FEAT_/8)) * 8;
    int slot_sw = ((col >> 3) & 3) ^ ((row >> 1) & 3);
    const float4* p = (const float4*)(roi + (size_t)i*8);
    *(bf16x8*)(Abf + (size_t)row*FEAT_ + (col & ~31) + slot_sw*8) = cvt8(p[0], p[1]);
  }
}

// ---------------- mid: Q-GEMM (BK=64) + small GEMMs + posbias, XCD-aware roles ----
// bx -> (x = bx&7 [XCD], j = bx>>3); j -> group g = j/22, slot r = j%22:
//   r<6   : role A, slab g of XCD x (mbase=(x+8g)*128), ntile r  -> 768 blocks
//   r<12  : role B small GEMMs                                  -> 768 blocks
//   else  : role C posbias                                      -> 1280 blocks
// Role A: 2 k-steps (BK=64) per barrier pair: 12 iters, 24 barriers (was 48).
// Role C rides in role A's stall bubbles (m114 MFMA/BW co-residency).
__global__ __launch_bounds__(256, 2) void mid_kernel(
    const bf16* __restrict__ Abf, const float* __restrict__ roi,
    const bf16* __restrict__ Wq_t,
    const float* __restrict__ bq, bf16* __restrict__ qbuf,
    const bf16* __restrict__ Wk_t, const bf16* __restrict__ Vbf,
    const bf16* __restrict__ Whi, const bf16* __restrict__ Wlo,
    const float* __restrict__ bk, bf16* __restrict__ kbuf,
    bf16* __restrict__ vwT_hi, bf16* __restrict__ vwT_lo,
    const float* __restrict__ pe, const float* __restrict__ Wpos,
    const float* __restrict__ bpos, float* __restrict__ posb)
{
  __shared__ __align__(16) bf16 smem[16384];     // 32 KB
  const int tid = threadIdx.x;
  const int w = tid >> 6, l = tid & 63;
  const int x = blockIdx.x & 7, j = blockIdx.x >> 3;
  const int g = j / 22, r = j % 22;
  const int fr = l & 15, fq = l >> 4, fko = fq << 3;

  if (r < 6) {
    // ================= role A: Q-GEMM 128x128, BK=64 =================
    bf16* sA = smem;                 // 2 sub-buffers [128][32] at 0 / +4096
    bf16* sB = smem + 8192;
    const int mbase = (x + 8*g) * 128;
    const int nbase = r * 128;
    const int wr = w >> 1, wc = w & 1;
    const int srow = tid >> 2;
    const int scol = (tid & 3) << 3;
    const bf16* Ag0 = Abf + (size_t)(mbase + srow)*FEAT_ + scol;
    const bf16* Ag1 = Ag0 + (size_t)64*FEAT_;
    const bf16* Bg0 = Wq_t + (size_t)(nbase + srow)*FEAT_ + scol;
    const bf16* Bg1 = Bg0 + (size_t)64*FEAT_;
    const int fko_sw = ((fq ^ ((fr >> 1) & 3)) << 3);
    f32x4 acc[4][4] = {};
    // prologue: stage k-steps 0,1
    gload16(Bg0, sB + w*512);          gload16(Bg1, sB + 2048 + w*512);
    gload16(Bg0 + 32, sB + 4096 + w*512); gload16(Bg1 + 32, sB + 6144 + w*512);
    gload16(Ag0, sA + w*512);          gload16(Ag1, sA + 2048 + w*512);
    gload16(Ag0 + 32, sA + 4096 + w*512); gload16(Ag1 + 32, sA + 6144 + w*512);
    __syncthreads();
    for (int t = 0; t < 12; ++t) {
      #pragma unroll
      for (int half = 0; half < 2; ++half) {
        const int bo = half * 4096;
        bf16x8 af[4], bff[4];
        #pragma unroll
        for (int m = 0; m < 4; ++m)
          af[m] = *(const bf16x8*)(sA + bo + (wr*64 + m*16 + fr)*32 + fko_sw);
        #pragma unroll
        for (int n = 0; n < 4; ++n)
          bff[n] = *(const bf16x8*)(sB + bo + (wc*64 + n*16 + fr)*32 + fko_sw);
        #pragma unroll
        for (int m = 0; m < 4; ++m) {
          #pragma unroll
          for (int n = 0; n < 4; ++n)
            acc[m][n] = __builtin_amdgcn_mfma_f32_16x16x32_bf16(af[m], bff[n], acc[m][n], 0, 0, 0);
        }
      }
      __syncthreads();                 // all reads of both sub-buffers done
      if (t < 11) {
        const int ko = (t + 1) * 64;
        gload16(Bg0 + ko, sB + w*512);           gload16(Bg1 + ko, sB + 2048 + w*512);
        gload16(Bg0 + ko + 32, sB + 4096 + w*512); gload16(Bg1 + ko + 32, sB + 6144 + w*512);
        gload16(Ag0 + ko, sA + w*512);           gload16(Ag1 + ko, sA + 2048 + w*512);
        gload16(Ag0 + ko + 32, sA + 4096 + w*512); gload16(Ag1 + ko + 32, sA + 6144 + w*512);
      }
      __syncthreads();                 // drain staging
    }
    #pragma unroll
    for (int n = 0; n < 4; ++n) {
      const int col = nbase + wc*64 + n*16 + fr;
      const float bv = bq[col];
      #pragma unroll
      for (int m = 0; m < 4; ++m) {
        const int row = mbase + wr*64 + m*16 + fq*4;
        #pragma unroll
        for (int rr = 0; rr < 4; ++rr)
          qbuf[(size_t)(row + rr)*FEAT_ + col] = (bf16)(acc[m][n][rr] + bv);
      }
    }
  } else if (r < 12) {
    // ================= role B: small GEMMs, one wave per 16x16 tile =================
    const int widx = (x*96 + g*6 + (r - 6))*4 + w;   // [0, 3072)
    const int cbase = (widx % 48) * 16;
    const int by = widx / 48;                        // [0,64)
    f32x4 acc = {};
    if (by < 32) {
      const float* Ap = roi + ((size_t)(by >> 1)*N_ + (by & 1)*16 + fr)*FEAT_ + fko;
      const bf16* Bp = Wk_t + (size_t)(cbase + fr)*FEAT_ + fko;
      #pragma unroll
      for (int kt = 0; kt < FEAT_/32; ++kt) {
        float4 a0 = *(const float4*)(Ap + kt*32);
        float4 a1 = *(const float4*)(Ap + kt*32 + 4);
        bf16x8 b = *(const bf16x8*)(Bp + kt*32);
        acc = __builtin_amdgcn_mfma_f32_16x16x32_bf16(cvt8(a0, a1), b, acc, 0, 0, 0);
      }
      const float bv = bk[cbase + fr];
      #pragma unroll
      for (int rr = 0; rr < 4; ++rr) {
        const int rl = (by & 1)*16 + fq*4 + rr;
        if (rl < NONGT_)
          kbuf[((size_t)(by >> 1)*KPAD_ + rl)*FEAT_ + cbase + fr] = (bf16)(acc[rr] + bv);
      }
    } else {
      const int rt = by - 32;
      const bf16* Ap = Vbf + ((size_t)rt*16 + fr)*FEAT_ + fko;
      const bf16* B1 = Whi + (size_t)(cbase + fr)*FEAT_ + fko;
      const bf16* B2 = Wlo + (size_t)(cbase + fr)*FEAT_ + fko;
      f32x4 acc2 = {};
      #pragma unroll
      for (int kt = 0; kt < FEAT_/32; ++kt) {
        bf16x8 a = *(const bf16x8*)(Ap + kt*32);
        acc  = __builtin_amdgcn_mfma_f32_16x16x32_bf16(a, *(const bf16x8*)(B1 + kt*32), acc,  0, 0, 0);
        acc2 = __builtin_amdgcn_mfma_f32_16x16x32_bf16(a, *(const bf16x8*)(B2 + kt*32), acc2, 0, 0, 0);
      }
      #pragma unroll
      for (int rr = 0; rr < 4; ++rr) {
        const int grow = rt*16 + fq*4 + rr;
        const int b = grow >> 5, key = grow & 31;
        float vv = acc[rr] + acc2[rr];
        bf16 vh = (bf16)vv;
        size_t addr = ((size_t)b*FEAT_ + cbase + fr)*KPAD_ + key;
        vwT_hi[addr] = vh;
        vwT_lo[addr] = (bf16)(vv - (float)vh);
      }
    }
  } else {
    // ================= role C: posbias, f64 accum, posb layout [row][j][h] =========
    float* sW = (float*)smem;                       // 512 floats
    float* sbp = (float*)smem + 512;
    sW[tid] = Wpos[tid];
    sW[256 + tid] = Wpos[256 + tid];
    if (tid < H_) sbp[tid] = bpos[tid];
    __syncthreads();
    const int pb = x*160 + g*10 + (r - 12);         // [0, 1280)
    const size_t gg = (size_t)pb*256 + tid;
    const float4* per = (const float4*)(pe + gg*POS_);
    double acc[8];
    #pragma unroll
    for (int h = 0; h < 8; ++h) acc[h] = (double)sbp[h];
    #pragma unroll
    for (int p4 = 0; p4 < 16; ++p4) {
      float4 a = per[p4];
      float av[4] = {a.x, a.y, a.z, a.w};
      #pragma unroll
      for (int e = 0; e < 4; ++e) {
        const double ad = (double)av[e];
        const float* wp = sW + (p4*4 + e)*8;
        #pragma unroll
        for (int h = 0; h < 8; ++h)
          acc[h] = fma(ad, (double)wp[h], acc[h]);
      }
    }
    float o[8];
    #pragma unroll
    for (int h = 0; h < 8; ++h) {
      float xx = (float)acc[h];
      o[h] = __logf(fmaxf(fmaxf(xx, 0.f), 1e-6f));
    }
    float4* po = (float4*)(posb + gg*8);
    po[0] = (float4){o[0], o[1], o[2], o[3]};
    po[1] = (float4){o[4], o[5], o[6], o[7]};
  }
}

// ---------------- fused attention: QK^T (MFMA) + softmax + PV (MFMA) ----------------
__global__ __launch_bounds__(256, 4) void attn_kernel(
    const bf16* __restrict__ qbuf, const bf16* __restrict__ kbuf,
    const bf16* __restrict__ vwT_hi, const bf16* __restrict__ vwT_lo,
    const float* __restrict__ posb, const int* __restrict__ adj,
    const float* __restrict__ lb, const float* __restrict__ bout,
    float* __restrict__ out)
{
  __shared__ __align__(16) bf16 sph[H_*16*40];
  __shared__ __align__(16) bf16 spl[H_*16*40];
  const int tid = threadIdx.x;
  const int w = tid >> 6, l = tid & 63;
  const int fr = l & 15, fq = l >> 4, fko = fq << 3;
  const int row0 = blockIdx.x * 16;
  const int b = blockIdx.y;
  const size_t rabs = (size_t)b*N_ + row0 + fr;

  #pragma unroll
  for (int hi2 = 0; hi2 < 2; ++hi2) {
    const int h = w*2 + hi2;
    const bf16* kp = kbuf + (size_t)b*KPAD_*FEAT_ + h*DG_ + fko;
    const bf16* qp = qbuf + rabs*FEAT_ + h*DG_ + fko;
    f32x4 acc0 = {}, acc1 = {};
    #pragma unroll
    for (int kt = 0; kt < 3; ++kt) {
      bf16x8 qa = *(const bf16x8*)(qp + kt*32);
      bf16x8 k0 = *(const bf16x8*)(kp + (size_t)fr*FEAT_ + kt*32);
      bf16x8 k1 = *(const bf16x8*)(kp + (size_t)(16 + fr)*FEAT_ + kt*32);
      acc0 = __builtin_amdgcn_mfma_f32_16x16x32_bf16(k0, qa, acc0, 0, 0, 0);
      acc1 = __builtin_amdgcn_mfma_f32_16x16x32_bf16(k1, qa, acc1, 0, 0, 0);
    }
    const float* pbr = posb + rabs*160;            // layout [j][h]
    const int*   adjr = adj + rabs*20;
    const float* lbr  = lb  + rabs*20;
    float lg[2][4];
    #pragma unroll
    for (int r = 0; r < 4; ++r) {
      int j0 = fq*4 + r;
      float v0 = acc0[r] * INV_SQRT_DG;
      v0 = (adjr[j0] > 0 ? v0 + pbr[j0*8 + h] : NEG_) + lbr[j0];
      lg[0][r] = v0;
      int j1 = 16 + fq*4 + r;
      float v1 = acc1[r] * INV_SQRT_DG;
      if (j1 < NONGT_)      v1 = (adjr[j1] > 0 ? v1 + pbr[j1*8 + h] : NEG_) + lbr[j1];
      else if (j1 >= KTOT_) v1 = -3.0e38f;
      lg[1][r] = v1;
    }
    float m = lg[0][0];
    #pragma unroll
    for (int jt = 0; jt < 2; ++jt)
      #pragma unroll
      for (int r = 0; r < 4; ++r) m = fmaxf(m, lg[jt][r]);
    m = fmaxf(m, __shfl_xor(m, 16));
    m = fmaxf(m, __shfl_xor(m, 32));
    float s = 0.f;
    float e[2][4];
    #pragma unroll
    for (int jt = 0; jt < 2; ++jt)
      #pragma unroll
      for (int r = 0; r < 4; ++r) { e[jt][r] = __expf(lg[jt][r] - m); s += e[jt][r]; }
    s += __shfl_xor(s, 16);
    s += __shfl_xor(s, 32);
    const float inv = 1.f / s;
    #pragma unroll
    for (int jt = 0; jt < 2; ++jt) {
      bf16x4 ph, pl;
      #pragma unroll
      for (int r = 0; r < 4; ++r) {
        float p = e[jt][r] * inv;
        ph[r] = (bf16)p;
        pl[r] = (bf16)(p - (float)ph[r]);
      }
      const int off = (h*16 + fr)*40 + jt*16 + fq*4;
      *(bf16x4*)(sph + off) = ph;
      *(bf16x4*)(spl + off) = pl;
    }
    bf16x8 pa_h = *(const bf16x8*)(sph + (h*16 + fr)*40 + fko);
    bf16x8 pa_l = *(const bf16x8*)(spl + (h*16 + fr)*40 + fko);
    #pragma unroll
    for (int ct = 0; ct < 6; ++ct) {
      const int col = h*DG_ + ct*16 + fr;
      const size_t vaddr = ((size_t)b*FEAT_ + col)*KPAD_ + fko;
      bf16x8 vh = *(const bf16x8*)(vwT_hi + vaddr);
      bf16x8 vl = *(const bf16x8*)(vwT_lo + vaddr);
      f32x4 o = {};
      o = __builtin_amdgcn_mfma_f32_16x16x32_bf16(pa_h, vh, o, 0, 0, 0);
      o = __builtin_amdgcn_mfma_f32_16x16x32_bf16(pa_h, vl, o, 0, 0, 0);
      o = __builtin_amdgcn_mfma_f32_16x16x32_bf16(pa_l, vh, o, 0, 0, 0);
      const float bv = bout[col];
      #pragma unroll
      for (int r = 0; r < 4; ++r)
        out[((size_t)b*N_ + row0 + fq*4 + r)*FEAT_ + col] = o[r] + bv;
    }
  }
}

extern "C" void kernel_launch(void* const* d_in, const int* in_sizes, int n_in,
                              void* d_out, int out_size, void* d_ws, size_t ws_size,
                              hipStream_t stream) {
  const float* roi  = (const float*)d_in[0];
  const int*   adj  = (const int*)  d_in[1];
  const float* pe   = (const float*)d_in[2];
  const float* lb   = (const float*)d_in[3];
  const float* aux  = (const float*)d_in[4];
  const float* Wq   = (const float*)d_in[5];
  const float* bq   = (const float*)d_in[6];
  const float* Wk   = (const float*)d_in[7];
  const float* bk   = (const float*)d_in[8];
  const float* Wpos = (const float*)d_in[9];
  const float* bpos = (const float*)d_in[10];
  const float* m_k  = (const float*)d_in[11];
  const float* m_v  = (const float*)d_in[12];
  const float* Wout = (const float*)d_in[13];
  const float* bout = (const float*)d_in[14];
  float* out = (float*)d_out;

  char* pw = (char*)d_ws;
  auto carve = [&](size_t bytes) -> void* {
    void* r = pw; pw += (bytes + 255) & ~(size_t)255; return r;
  };
  bf16*  Abf    = (bf16*) carve((size_t)ROWS_*FEAT_*2);
  bf16*  qbuf   = (bf16*) carve((size_t)ROWS_*FEAT_*2);
  bf16*  Wq_t   = (bf16*) carve((size_t)FEAT_*FEAT_*2);
  bf16*  Wk_t   = (bf16*) carve((size_t)FEAT_*FEAT_*2);
  bf16*  Whi    = (bf16*) carve((size_t)FEAT_*FEAT_*2);
  bf16*  Wlo    = (bf16*) carve((size_t)FEAT_*FEAT_*2);
  bf16*  Vbf    = (bf16*) carve((size_t)B_*KPAD_*FEAT_*2);
  bf16*  kbuf   = (bf16*) carve((size_t)B_*KPAD_*FEAT_*2);
  bf16*  vwT_hi = (bf16*) carve((size_t)B_*FEAT_*KPAD_*2);
  bf16*  vwT_lo = (bf16*) carve((size_t)B_*FEAT_*KPAD_*2);
  float* posb   = (float*)carve((size_t)ROWS_*160*4);

  prep_kernel<<<dim3(2048), dim3(256), 0, stream>>>(Wq, Wk, Wout, roi, aux, m_v, m_k,
                                                    Wq_t, Wk_t, Whi, Wlo, Vbf, kbuf, Abf);
  mid_kernel<<<dim3(2816), dim3(256), 0, stream>>>(Abf, roi, Wq_t, bq, qbuf,
                                                   Wk_t, Vbf, Whi, Wlo, bk, kbuf,
                                                   vwT_hi, vwT_lo,
                                                   pe, Wpos, bpos, posb);
  attn_kernel<<<dim3(64, 16), dim3(256), 0, stream>>>(qbuf, kbuf, vwT_hi, vwT_lo,
                                                      posb, adj, lb, bout, out);
}